// Round 6
// baseline (323.668 us; speedup 1.0000x reference)
//
#include <hip/hip_runtime.h>
#include <hip/hip_bf16.h>
#include <math.h>

typedef unsigned short u16;
typedef unsigned int u32;
typedef u16 u16x4 __attribute__((ext_vector_type(4)));
typedef u16 u16x8 __attribute__((ext_vector_type(8)));
typedef short bf16x8 __attribute__((ext_vector_type(8)));
typedef float f32x4 __attribute__((ext_vector_type(4)));

// N=2, L=2048, E=1024, H=16, D=64
#define LSEQ 2048
#define NH   32

// Q-projection scale: 1/sqrt(64) * log2(e)  -> flash uses exp2f directly
#define QSCALE 0.18033688011112042f

__device__ __forceinline__ u16 f2bf(float f) {
    __hip_bfloat16 h = __float2bfloat16(f);
    union { __hip_bfloat16 h; u16 u; } c; c.h = h; return c.u;
}

// -----------------------------------------------------------------------
// f32 -> bf16 vectorized convert (grid-stride, float4 granularity)
// -----------------------------------------------------------------------
__global__ __launch_bounds__(256) void cvt_bf16(
    const float* __restrict__ src, u16* __restrict__ dst, int n4)
{
    int stride = gridDim.x * 256;
    for (int i = blockIdx.x * 256 + threadIdx.x; i < n4; i += stride) {
        float4 a = ((const float4*)src)[i];
        u16x4 p;
        p[0] = f2bf(a.x); p[1] = f2bf(a.y); p[2] = f2bf(a.z); p[3] = f2bf(a.w);
        ((u16x4*)dst)[i] = p;
    }
}

// -----------------------------------------------------------------------
// GEMM v3: C[m,n] = sum_k A[m,k]*W[n,k] + bias[n]
// A bf16 [4096][1024]; W f32 [1024][1024] (bf16-converted during staging).
// BM=64, BN=64, BK=64; grid (16,64) = 1024 blocks (4/CU); 4 waves (2x2),
// wave tile 32x32. Linear 128B LDS rows + XOR slot swizzle (col16 ^= row&7):
// A staged with pre-swizzled SOURCE col + linear dest, B dest-swizzled
// u16x4 writes. Double-buffered, reg prologue, ONE barrier per K-step.
// MODE 0: bf16 [N,H,L,D]; MODE 1: bf16 [N,H,D,L]; MODE 2: f32 [M,E].
// QS!=0: scale output by QSCALE (Q projection).
// -----------------------------------------------------------------------
template<int MODE, int QS>
__global__ __launch_bounds__(256, 4) void proj_gemm3(
    const u16* __restrict__ A, const float* __restrict__ W,
    const float* __restrict__ bias, void* __restrict__ Out)
{
    __shared__ u16 Al[2][64 * 64];    // 8 KB per buf
    __shared__ u16 Bl[2][64 * 64];    // 8 KB per buf

    const int tid  = threadIdx.x;
    const int lane = tid & 63;
    const int w    = tid >> 6;
    const int lr   = lane & 15, lg = lane >> 4;
    const int t8   = tid & 7,   td8 = tid >> 3;   // A staging coords (32 rows)
    const int brow = tid >> 4,  bc8 = tid & 15;   // B staging coords (16 rows)
    const int m0   = blockIdx.y * 64;
    const int n0   = blockIdx.x * 64;
    const int wr   = (w >> 1) * 32;
    const int wc   = (w & 1) * 32;
    const int ascol = (t8 ^ (td8 & 7)) * 8;       // pre-swizzled A source col

    f32x4 acc[2][2] = {};
    u16x8 ra[2];
    float4 rb[4];

    #define LOADS(k0)                                                          \
        _Pragma("unroll")                                                      \
        for (int p_ = 0; p_ < 2; ++p_)                                         \
            ra[p_] = *(const u16x8*)(A + (size_t)(m0 + p_ * 32 + td8) * 1024   \
                                     + (k0) + ascol);                          \
        _Pragma("unroll")                                                      \
        for (int p_ = 0; p_ < 4; ++p_)                                         \
            rb[p_] = *(const float4*)(W + (size_t)(n0 + p_ * 16 + brow) * 1024 \
                                      + (k0) + bc8 * 4);
    #define WRITE(buf)                                                         \
        _Pragma("unroll")                                                      \
        for (int p_ = 0; p_ < 2; ++p_)                                         \
            *(u16x8*)((char*)&Al[buf][0] + (p_ * 32 + td8) * 128 + t8 * 16)    \
                = ra[p_];                                                      \
        _Pragma("unroll")                                                      \
        for (int p_ = 0; p_ < 4; ++p_) {                                       \
            u16x4 pw_;                                                         \
            pw_[0] = f2bf(rb[p_].x); pw_[1] = f2bf(rb[p_].y);                  \
            pw_[2] = f2bf(rb[p_].z); pw_[3] = f2bf(rb[p_].w);                  \
            int row_ = p_ * 16 + brow;                                         \
            *(u16x4*)((char*)&Bl[buf][0] + row_ * 128                          \
                      + ((bc8 * 8) ^ ((row_ & 7) << 4))) = pw_;                \
        }

    LOADS(0)
    WRITE(0)
    LOADS(64)
    __syncthreads();

    for (int t = 0; t < 16; ++t) {
        const int c = t & 1;
        if (t + 1 < 16) {
            WRITE(c ^ 1)
            if (t + 2 < 16) LOADS((t + 2) * 64)
        }
        const char* Ac = (const char*)&Al[c][0];
        const char* Bc = (const char*)&Bl[c][0];
        #pragma unroll
        for (int ks = 0; ks < 2; ++ks) {
            const int co = ((ks * 4 + lg) * 16) ^ ((lr & 7) << 4);
            bf16x8 af[2], bfr[2];
            #pragma unroll
            for (int i = 0; i < 2; ++i)
                af[i] = *(const bf16x8*)(Ac + (wr + i * 16 + lr) * 128 + co);
            #pragma unroll
            for (int j = 0; j < 2; ++j)
                bfr[j] = *(const bf16x8*)(Bc + (wc + j * 16 + lr) * 128 + co);
            #pragma unroll
            for (int i = 0; i < 2; ++i)
                #pragma unroll
                for (int j = 0; j < 2; ++j)
                    acc[i][j] = __builtin_amdgcn_mfma_f32_16x16x32_bf16(
                        af[i], bfr[j], acc[i][j], 0, 0, 0);
        }
        __syncthreads();
    }

    // epilogue
    #pragma unroll
    for (int j = 0; j < 2; ++j) {
        const int nn = n0 + wc + j * 16 + lr;
        const float bj = bias[nn];
        #pragma unroll
        for (int i = 0; i < 2; ++i) {
            #pragma unroll
            for (int r = 0; r < 4; ++r) {
                const int m = m0 + wr + i * 16 + lg * 4 + r;
                float vv = acc[i][j][r] + bj;
                if (QS) vv *= QSCALE;
                if (MODE == 0) {
                    const int n = m >> 11, l = m & 2047;
                    const int h = nn >> 6, d = nn & 63;
                    ((u16*)Out)[(((size_t)(n * 16 + h) * 2048) + l) * 64 + d] = f2bf(vv);
                } else if (MODE == 1) {
                    const int n = m >> 11, l = m & 2047;
                    const int h = nn >> 6, d = nn & 63;
                    ((u16*)Out)[(((size_t)(n * 16 + h) * 64) + d) * 2048 + l] = f2bf(vv);
                } else {
                    ((float*)Out)[(size_t)m * 1024 + nn] = vv;
                }
            }
        }
    }
    #undef LOADS
    #undef WRITE
}

// -----------------------------------------------------------------------
// Flash attention v5: block = 64 q rows of one (n,h); 4 waves x 16 rows.
// Grid (32,32) = 1024 blocks = 4 blocks/CU (16 waves/CU). K/V tiles in
// double-buffered swizzled LDS (source-swizzled staging, ds_write);
// ONE barrier per kv-tile. Softmax in exp2 domain (Q pre-scaled by
// 1/8*log2e). P in wave-private swizzled LDS.
// Qh,Kh: bf16 [NH][L][64]; Vt: bf16 [NH][64][L]; Oout: bf16 [N,L,E].
// -----------------------------------------------------------------------
__global__ __launch_bounds__(256, 4) void flash_attn5(
    const u16* __restrict__ Qh, const u16* __restrict__ Kh,
    const u16* __restrict__ Vt, u16* __restrict__ Oout)
{
    const int tid  = threadIdx.x;
    const int lane = tid & 63;
    const int w    = tid >> 6;
    const int lr   = lane & 15, lg = lane >> 4;
    const int t8   = tid & 7,   td8 = tid >> 3;
    const int nh   = blockIdx.y;
    const int q0   = blockIdx.x * 64;
    const int scol = (t8 ^ (td8 & 7)) * 8;   // pre-swizzled source col (elems)

    const u16* Qb = Qh + (size_t)nh * LSEQ * 64;
    const u16* Kb = Kh + (size_t)nh * LSEQ * 64;
    const u16* Vb = Vt + (size_t)nh * 64 * LSEQ;

    __shared__ u16 Kl[2][64 * 64];   // [s][d] swizzled, 8 KB per buf
    __shared__ u16 Vl[2][64 * 64];   // [d][s] swizzled, 8 KB per buf
    __shared__ u16 Pl[4][16 * 64];   // wave-private, swizzled, 2 KB per wave

    // Q fragments (already scaled by QSCALE): rows q0 + w*16 + lr
    bf16x8 aq[2];
    #pragma unroll
    for (int ks = 0; ks < 2; ++ks)
        aq[ks] = *(const bf16x8*)(Qb +
            (size_t)(q0 + w * 16 + lr) * 64 + ks * 32 + lg * 8);

    float m_run[4], l_run[4];
    f32x4 Oacc[4] = {};
    #pragma unroll
    for (int r = 0; r < 4; ++r) { m_run[r] = -INFINITY; l_run[r] = 0.f; }

    u16x8 ldK0, ldK1, ldV0, ldV1;
    #define LOADS(s0)                                                          \
        ldK0 = *(const u16x8*)(Kb + (size_t)((s0) + td8) * 64 + scol);         \
        ldK1 = *(const u16x8*)(Kb + (size_t)((s0) + td8 + 32) * 64 + scol);    \
        ldV0 = *(const u16x8*)(Vb + (size_t)td8 * LSEQ + (s0) + scol);         \
        ldV1 = *(const u16x8*)(Vb + (size_t)(td8 + 32) * LSEQ + (s0) + scol);
    #define WRITE(buf)                                                         \
        *(u16x8*)((char*)&Kl[buf][0] + td8 * 128 + t8 * 16)        = ldK0;     \
        *(u16x8*)((char*)&Kl[buf][0] + (td8 + 32) * 128 + t8 * 16) = ldK1;     \
        *(u16x8*)((char*)&Vl[buf][0] + td8 * 128 + t8 * 16)        = ldV0;     \
        *(u16x8*)((char*)&Vl[buf][0] + (td8 + 32) * 128 + t8 * 16) = ldV1;

    LOADS(0)
    WRITE(0)
    LOADS(64)
    __syncthreads();

    for (int t = 0; t < LSEQ / 64; ++t) {
        const int c = t & 1;
        if (t + 1 < LSEQ / 64) {
            WRITE(c ^ 1)
            if (t + 2 < LSEQ / 64) LOADS((t + 2) * 64)
        }
        const char* Kc = (const char*)&Kl[c][0];
        const char* Vc = (const char*)&Vl[c][0];
        char* Pw = (char*)&Pl[w][0];

        // ---- S = Q K^T (exp2 domain) ----
        f32x4 S[4] = {};
        #pragma unroll
        for (int ks = 0; ks < 2; ++ks) {
            const int co = ((ks * 4 + lg) * 16) ^ ((lr & 7) << 4);
            #pragma unroll
            for (int ct = 0; ct < 4; ++ct) {
                bf16x8 kb = *(const bf16x8*)(Kc + (ct * 16 + lr) * 128 + co);
                S[ct] = __builtin_amdgcn_mfma_f32_16x16x32_bf16(
                    aq[ks], kb, S[ct], 0, 0, 0);
            }
        }

        // ---- online softmax (wave-private) ----
        {
            float m_new[4], sf[4], rs[4];
            #pragma unroll
            for (int r = 0; r < 4; ++r) {
                float tm = fmaxf(fmaxf(S[0][r], S[1][r]), fmaxf(S[2][r], S[3][r]));
                #pragma unroll
                for (int mk = 1; mk <= 8; mk <<= 1)
                    tm = fmaxf(tm, __shfl_xor(tm, mk, 64));
                m_new[r] = fmaxf(m_run[r], tm);
                sf[r] = exp2f(m_run[r] - m_new[r]);
                m_run[r] = m_new[r];
                rs[r] = 0.f;
            }
            #pragma unroll
            for (int ct = 0; ct < 4; ++ct)
                #pragma unroll
                for (int r = 0; r < 4; ++r) {
                    float p = exp2f(S[ct][r] - m_new[r]);
                    rs[r] += p;
                    int pr = lg * 4 + r;
                    *(u16*)(Pw + pr * 128 +
                            (((ct * 16 + lr) * 2) ^ ((pr & 7) << 4))) = f2bf(p);
                }
            #pragma unroll
            for (int r = 0; r < 4; ++r) {
                float s = rs[r];
                #pragma unroll
                for (int mk = 1; mk <= 8; mk <<= 1)
                    s += __shfl_xor(s, mk, 64);
                l_run[r] = l_run[r] * sf[r] + s;
            }
            #pragma unroll
            for (int dt = 0; dt < 4; ++dt)
                #pragma unroll
                for (int r = 0; r < 4; ++r)
                    Oacc[dt][r] *= sf[r];
        }

        // ---- O += P V ----
        #pragma unroll
        for (int ks = 0; ks < 2; ++ks) {
            const int co = ((ks * 4 + lg) * 16) ^ ((lr & 7) << 4);
            bf16x8 pa = *(const bf16x8*)(Pw + lr * 128 + co);
            #pragma unroll
            for (int dt = 0; dt < 4; ++dt) {
                bf16x8 vb = *(const bf16x8*)(Vc + (dt * 16 + lr) * 128 + co);
                Oacc[dt] = __builtin_amdgcn_mfma_f32_16x16x32_bf16(
                    pa, vb, Oacc[dt], 0, 0, 0);
            }
        }
        __syncthreads();
    }
    #undef LOADS
    #undef WRITE

    // ---- epilogue: attn_out bf16 [N, L, H*D] ----
    const int n = nh >> 4, h = nh & 15;
    #pragma unroll
    for (int dt = 0; dt < 4; ++dt)
        #pragma unroll
        for (int r = 0; r < 4; ++r) {
            float o = Oacc[dt][r] / l_run[r];
            int qq = q0 + w * 16 + lg * 4 + r;
            Oout[((size_t)(n * LSEQ + qq)) * 1024 + h * 64 + dt * 16 + lr] = f2bf(o);
        }
}

extern "C" void kernel_launch(void* const* d_in, const int* in_sizes, int n_in,
                              void* d_out, int out_size, void* d_ws, size_t ws_size,
                              hipStream_t stream) {
    const float* q  = (const float*)d_in[0];
    const float* k  = (const float*)d_in[1];
    const float* v  = (const float*)d_in[2];
    const float* Wq = (const float*)d_in[3];
    const float* bq = (const float*)d_in[4];
    const float* Wk = (const float*)d_in[5];
    const float* bk = (const float*)d_in[6];
    const float* Wv = (const float*)d_in[7];
    const float* bv = (const float*)d_in[8];
    const float* Wo = (const float*)d_in[9];
    const float* bo = (const float*)d_in[10];

    // ws (u16 units), 32 MB total, slot-rotated:
    //   S1=Qh, S2=Kh, S3=Vt, S4=scratch (bf16 input, then attn-out)
    u16* ws = (u16*)d_ws;
    u16* Qh = ws;
    u16* Kh = ws + (size_t)4 * 1024 * 1024;
    u16* Vt = ws + (size_t)8 * 1024 * 1024;
    u16* S4 = ws + (size_t)12 * 1024 * 1024;

    const int n4 = (2 * LSEQ * 1024) / 4;
    dim3 cg(2048), cb(256);
    dim3 gg(16, 64), gb(256);   // GEMM: x = N/64, y = M/64

    cvt_bf16<<<cg, cb, 0, stream>>>(q, S4, n4);
    proj_gemm3<0, 1><<<gg, gb, 0, stream>>>(S4, Wq, bq, Qh);
    cvt_bf16<<<cg, cb, 0, stream>>>(k, S4, n4);
    proj_gemm3<0, 0><<<gg, gb, 0, stream>>>(S4, Wk, bk, Kh);
    cvt_bf16<<<cg, cb, 0, stream>>>(v, S4, n4);
    proj_gemm3<1, 0><<<gg, gb, 0, stream>>>(S4, Wv, bv, Vt);
    flash_attn5<<<dim3(LSEQ / 64, NH), gb, 0, stream>>>(Qh, Kh, Vt, S4);
    proj_gemm3<2, 0><<<gg, gb, 0, stream>>>(S4, Wo, bo, (float*)d_out);
}

// Round 7
// 309.857 us; speedup vs baseline: 1.0446x; 1.0446x over previous
//
#include <hip/hip_runtime.h>
#include <hip/hip_bf16.h>
#include <math.h>

typedef unsigned short u16;
typedef unsigned int u32;
typedef u16 u16x4 __attribute__((ext_vector_type(4)));
typedef u16 u16x8 __attribute__((ext_vector_type(8)));
typedef short bf16x8 __attribute__((ext_vector_type(8)));
typedef float f32x4 __attribute__((ext_vector_type(4)));

// N=2, L=2048, E=1024, H=16, D=64
#define LSEQ 2048
#define NH   32

// Q-projection scale: 1/sqrt(64) * log2(e)  -> flash uses exp2f directly
#define QSCALE 0.18033688011112042f

__device__ __forceinline__ u16 f2bf(float f) {
    __hip_bfloat16 h = __float2bfloat16(f);
    union { __hip_bfloat16 h; u16 u; } c; c.h = h; return c.u;
}

// -----------------------------------------------------------------------
// f32 -> bf16 vectorized convert (grid-stride, float4 granularity)
// -----------------------------------------------------------------------
__global__ __launch_bounds__(256) void cvt_bf16(
    const float* __restrict__ src, u16* __restrict__ dst, int n4)
{
    int stride = gridDim.x * 256;
    for (int i = blockIdx.x * 256 + threadIdx.x; i < n4; i += stride) {
        float4 a = ((const float4*)src)[i];
        u16x4 p;
        p[0] = f2bf(a.x); p[1] = f2bf(a.y); p[2] = f2bf(a.z); p[3] = f2bf(a.w);
        ((u16x4*)dst)[i] = p;
    }
}

// three weight matrices (1M f32 each) -> contiguous bf16
__global__ __launch_bounds__(256) void cvt3_bf16(
    const float* __restrict__ s0, const float* __restrict__ s1,
    const float* __restrict__ s2, u16* __restrict__ dst)
{
    int i = blockIdx.x * 256 + threadIdx.x;      // 0 .. 3*(1<<18)-1
    const float* s = (i < (1 << 18)) ? s0 : (i < (2 << 18)) ? s1 : s2;
    int off = i & ((1 << 18) - 1);
    float4 a = ((const float4*)s)[off];
    u16x4 p;
    p[0] = f2bf(a.x); p[1] = f2bf(a.y); p[2] = f2bf(a.z); p[3] = f2bf(a.w);
    ((u16x4*)dst)[i] = p;
}

// -----------------------------------------------------------------------
// GEMM v4: C[m,n] = sum_k A[m,k]*W[n,k] + bias[n]   (A, W both bf16)
// BM=BN=128, BK=64; grid (8,32) = 256 blocks (1/CU); 4 waves (2x2),
// wave tile 64x64: 32 MFMA : 8 ds_read_b128 per K-step (2:1). Linear
// 128B LDS rows + XOR slot swizzle (col16 ^= row&7), staged with
// pre-swizzled SOURCE col + linear dest (conflict-free both sides).
// Double-buffered, reg prologue, ONE barrier per K-step; compute phase
// (~400cyc) covers the L2 latency of the in-flight prefetch so the
// compiler's vmcnt(0)-before-barrier drain is ~free.
// MODE 0: bf16 [N,H,L,D]; MODE 1: bf16 [N,H,D,L]; MODE 2: f32 [M,E].
// QS!=0: scale output by QSCALE (Q projection).
// -----------------------------------------------------------------------
template<int MODE, int QS>
__global__ __launch_bounds__(256, 1) void proj_gemm4(
    const u16* __restrict__ A, const u16* __restrict__ W,
    const float* __restrict__ bias, void* __restrict__ Out)
{
    __shared__ u16 Al[2][128 * 64];   // 16 KB per buf
    __shared__ u16 Bl[2][128 * 64];   // 16 KB per buf

    const int tid  = threadIdx.x;
    const int lane = tid & 63;
    const int w    = tid >> 6;
    const int lr   = lane & 15, lg = lane >> 4;
    const int m0   = blockIdx.y * 128;
    const int n0   = blockIdx.x * 128;
    const int wr   = (w >> 1) * 64;
    const int wc   = (w & 1) * 64;
    // staging: chunk c = p*256+tid covers row = p*32 + (tid>>3), col8 = tid&7
    const int srow = tid >> 3;                    // 0..31
    const int sc8  = tid & 7;
    const int ssw  = (sc8 ^ (srow & 7)) * 8;      // pre-swizzled source col

    f32x4 acc[4][4] = {};
    u16x8 ra[4], rb[4];

    #define LOADS(k0)                                                          \
        _Pragma("unroll")                                                      \
        for (int p_ = 0; p_ < 4; ++p_) {                                       \
            ra[p_] = *(const u16x8*)(A + (size_t)(m0 + p_ * 32 + srow) * 1024  \
                                     + (k0) + ssw);                            \
            rb[p_] = *(const u16x8*)(W + (size_t)(n0 + p_ * 32 + srow) * 1024  \
                                     + (k0) + ssw);                            \
        }
    #define WRITE(buf)                                                         \
        _Pragma("unroll")                                                      \
        for (int p_ = 0; p_ < 4; ++p_) {                                       \
            *(u16x8*)((char*)&Al[buf][0] + (p_ * 32 + srow) * 128 + sc8 * 16)  \
                = ra[p_];                                                      \
            *(u16x8*)((char*)&Bl[buf][0] + (p_ * 32 + srow) * 128 + sc8 * 16)  \
                = rb[p_];                                                      \
        }

    LOADS(0)
    WRITE(0)
    LOADS(64)
    __syncthreads();

    for (int t = 0; t < 16; ++t) {
        const int c = t & 1;
        if (t + 1 < 16) {
            WRITE(c ^ 1)
            if (t + 2 < 16) LOADS((t + 2) * 64)
        }
        const char* Ac = (const char*)&Al[c][0];
        const char* Bc = (const char*)&Bl[c][0];
        #pragma unroll
        for (int ks = 0; ks < 2; ++ks) {
            const int co = ((ks * 4 + lg) * 16) ^ ((lr & 7) << 4);
            bf16x8 af[4], bfr[4];
            #pragma unroll
            for (int i = 0; i < 4; ++i)
                af[i] = *(const bf16x8*)(Ac + (wr + i * 16 + lr) * 128 + co);
            #pragma unroll
            for (int j = 0; j < 4; ++j)
                bfr[j] = *(const bf16x8*)(Bc + (wc + j * 16 + lr) * 128 + co);
            #pragma unroll
            for (int i = 0; i < 4; ++i)
                #pragma unroll
                for (int j = 0; j < 4; ++j)
                    acc[i][j] = __builtin_amdgcn_mfma_f32_16x16x32_bf16(
                        af[i], bfr[j], acc[i][j], 0, 0, 0);
        }
        __syncthreads();
    }

    // epilogue
    #pragma unroll
    for (int j = 0; j < 4; ++j) {
        const int nn = n0 + wc + j * 16 + lr;
        const float bj = bias[nn];
        #pragma unroll
        for (int i = 0; i < 4; ++i) {
            #pragma unroll
            for (int r = 0; r < 4; ++r) {
                const int m = m0 + wr + i * 16 + lg * 4 + r;
                float vv = acc[i][j][r] + bj;
                if (QS) vv *= QSCALE;
                if (MODE == 0) {
                    const int n = m >> 11, l = m & 2047;
                    const int h = nn >> 6, d = nn & 63;
                    ((u16*)Out)[(((size_t)(n * 16 + h) * 2048) + l) * 64 + d] = f2bf(vv);
                } else if (MODE == 1) {
                    const int n = m >> 11, l = m & 2047;
                    const int h = nn >> 6, d = nn & 63;
                    ((u16*)Out)[(((size_t)(n * 16 + h) * 64) + d) * 2048 + l] = f2bf(vv);
                } else {
                    ((float*)Out)[(size_t)m * 1024 + nn] = vv;
                }
            }
        }
    }
    #undef LOADS
    #undef WRITE
}

// -----------------------------------------------------------------------
// Flash attention v5 (unchanged from R6): block = 64 q rows; 4 waves x 16.
// -----------------------------------------------------------------------
__global__ __launch_bounds__(256, 4) void flash_attn5(
    const u16* __restrict__ Qh, const u16* __restrict__ Kh,
    const u16* __restrict__ Vt, u16* __restrict__ Oout)
{
    const int tid  = threadIdx.x;
    const int lane = tid & 63;
    const int w    = tid >> 6;
    const int lr   = lane & 15, lg = lane >> 4;
    const int t8   = tid & 7,   td8 = tid >> 3;
    const int nh   = blockIdx.y;
    const int q0   = blockIdx.x * 64;
    const int scol = (t8 ^ (td8 & 7)) * 8;   // pre-swizzled source col (elems)

    const u16* Qb = Qh + (size_t)nh * LSEQ * 64;
    const u16* Kb = Kh + (size_t)nh * LSEQ * 64;
    const u16* Vb = Vt + (size_t)nh * 64 * LSEQ;

    __shared__ u16 Kl[2][64 * 64];   // [s][d] swizzled, 8 KB per buf
    __shared__ u16 Vl[2][64 * 64];   // [d][s] swizzled, 8 KB per buf
    __shared__ u16 Pl[4][16 * 64];   // wave-private, swizzled, 2 KB per wave

    bf16x8 aq[2];
    #pragma unroll
    for (int ks = 0; ks < 2; ++ks)
        aq[ks] = *(const bf16x8*)(Qb +
            (size_t)(q0 + w * 16 + lr) * 64 + ks * 32 + lg * 8);

    float m_run[4], l_run[4];
    f32x4 Oacc[4] = {};
    #pragma unroll
    for (int r = 0; r < 4; ++r) { m_run[r] = -INFINITY; l_run[r] = 0.f; }

    u16x8 ldK0, ldK1, ldV0, ldV1;
    #define LOADS(s0)                                                          \
        ldK0 = *(const u16x8*)(Kb + (size_t)((s0) + td8) * 64 + scol);         \
        ldK1 = *(const u16x8*)(Kb + (size_t)((s0) + td8 + 32) * 64 + scol);    \
        ldV0 = *(const u16x8*)(Vb + (size_t)td8 * LSEQ + (s0) + scol);         \
        ldV1 = *(const u16x8*)(Vb + (size_t)(td8 + 32) * LSEQ + (s0) + scol);
    #define WRITE(buf)                                                         \
        *(u16x8*)((char*)&Kl[buf][0] + td8 * 128 + t8 * 16)        = ldK0;     \
        *(u16x8*)((char*)&Kl[buf][0] + (td8 + 32) * 128 + t8 * 16) = ldK1;     \
        *(u16x8*)((char*)&Vl[buf][0] + td8 * 128 + t8 * 16)        = ldV0;     \
        *(u16x8*)((char*)&Vl[buf][0] + (td8 + 32) * 128 + t8 * 16) = ldV1;

    LOADS(0)
    WRITE(0)
    LOADS(64)
    __syncthreads();

    for (int t = 0; t < LSEQ / 64; ++t) {
        const int c = t & 1;
        if (t + 1 < LSEQ / 64) {
            WRITE(c ^ 1)
            if (t + 2 < LSEQ / 64) LOADS((t + 2) * 64)
        }
        const char* Kc = (const char*)&Kl[c][0];
        const char* Vc = (const char*)&Vl[c][0];
        char* Pw = (char*)&Pl[w][0];

        // ---- S = Q K^T (exp2 domain) ----
        f32x4 S[4] = {};
        #pragma unroll
        for (int ks = 0; ks < 2; ++ks) {
            const int co = ((ks * 4 + lg) * 16) ^ ((lr & 7) << 4);
            #pragma unroll
            for (int ct = 0; ct < 4; ++ct) {
                bf16x8 kb = *(const bf16x8*)(Kc + (ct * 16 + lr) * 128 + co);
                S[ct] = __builtin_amdgcn_mfma_f32_16x16x32_bf16(
                    aq[ks], kb, S[ct], 0, 0, 0);
            }
        }

        // ---- online softmax (wave-private) ----
        {
            float m_new[4], sf[4], rs[4];
            #pragma unroll
            for (int r = 0; r < 4; ++r) {
                float tm = fmaxf(fmaxf(S[0][r], S[1][r]), fmaxf(S[2][r], S[3][r]));
                #pragma unroll
                for (int mk = 1; mk <= 8; mk <<= 1)
                    tm = fmaxf(tm, __shfl_xor(tm, mk, 64));
                m_new[r] = fmaxf(m_run[r], tm);
                sf[r] = exp2f(m_run[r] - m_new[r]);
                m_run[r] = m_new[r];
                rs[r] = 0.f;
            }
            #pragma unroll
            for (int ct = 0; ct < 4; ++ct)
                #pragma unroll
                for (int r = 0; r < 4; ++r) {
                    float p = exp2f(S[ct][r] - m_new[r]);
                    rs[r] += p;
                    int pr = lg * 4 + r;
                    *(u16*)(Pw + pr * 128 +
                            (((ct * 16 + lr) * 2) ^ ((pr & 7) << 4))) = f2bf(p);
                }
            #pragma unroll
            for (int r = 0; r < 4; ++r) {
                float s = rs[r];
                #pragma unroll
                for (int mk = 1; mk <= 8; mk <<= 1)
                    s += __shfl_xor(s, mk, 64);
                l_run[r] = l_run[r] * sf[r] + s;
            }
            #pragma unroll
            for (int dt = 0; dt < 4; ++dt)
                #pragma unroll
                for (int r = 0; r < 4; ++r)
                    Oacc[dt][r] *= sf[r];
        }

        // ---- O += P V ----
        #pragma unroll
        for (int ks = 0; ks < 2; ++ks) {
            const int co = ((ks * 4 + lg) * 16) ^ ((lr & 7) << 4);
            bf16x8 pa = *(const bf16x8*)(Pw + lr * 128 + co);
            #pragma unroll
            for (int dt = 0; dt < 4; ++dt) {
                bf16x8 vb = *(const bf16x8*)(Vc + (dt * 16 + lr) * 128 + co);
                Oacc[dt] = __builtin_amdgcn_mfma_f32_16x16x32_bf16(
                    pa, vb, Oacc[dt], 0, 0, 0);
            }
        }
        __syncthreads();
    }
    #undef LOADS
    #undef WRITE

    // ---- epilogue: attn_out bf16 [N, L, H*D] ----
    const int n = nh >> 4, h = nh & 15;
    #pragma unroll
    for (int dt = 0; dt < 4; ++dt)
        #pragma unroll
        for (int r = 0; r < 4; ++r) {
            float o = Oacc[dt][r] / l_run[r];
            int qq = q0 + w * 16 + lg * 4 + r;
            Oout[((size_t)(n * LSEQ + qq)) * 1024 + h * 64 + dt * 16 + lr] = f2bf(o);
        }
}

extern "C" void kernel_launch(void* const* d_in, const int* in_sizes, int n_in,
                              void* d_out, int out_size, void* d_ws, size_t ws_size,
                              hipStream_t stream) {
    const float* q  = (const float*)d_in[0];
    const float* k  = (const float*)d_in[1];
    const float* v  = (const float*)d_in[2];
    const float* Wq = (const float*)d_in[3];
    const float* bq = (const float*)d_in[4];
    const float* Wk = (const float*)d_in[5];
    const float* bk = (const float*)d_in[6];
    const float* Wv = (const float*)d_in[7];
    const float* bv = (const float*)d_in[8];
    const float* Wo = (const float*)d_in[9];
    const float* bo = (const float*)d_in[10];

    // ws (u16 units), 32 MB: Qh | Kh | Vt | S4 (bf16 input / attn-out)
    u16* ws = (u16*)d_ws;
    u16* Qh = ws;
    u16* Kh = ws + (size_t)4 * 1024 * 1024;
    u16* Vt = ws + (size_t)8 * 1024 * 1024;
    u16* S4 = ws + (size_t)12 * 1024 * 1024;

    // d_out (16 MB f32) doubles as scratch until the final GEMM fully
    // overwrites it: Wq/Wk/Wv bf16 copies live in its first 6 MB.
    u16* Wb  = (u16*)d_out;
    u16* Wqb = Wb;
    u16* Wkb = Wb + (size_t)1 * 1024 * 1024;
    u16* Wvb = Wb + (size_t)2 * 1024 * 1024;

    const int n4in = (2 * LSEQ * 1024) / 4;  // q/k/v: 2M float4
    dim3 cb(256);
    dim3 gg(8, 32), gb(256);                 // GEMM: x = N/128, y = M/128

    cvt3_bf16<<<dim3(3 * 1024), cb, 0, stream>>>(Wq, Wk, Wv, Wb);
    cvt_bf16<<<dim3(2048), cb, 0, stream>>>(q, S4, n4in);
    proj_gemm4<0, 1><<<gg, gb, 0, stream>>>(S4, Wqb, bq, Qh);
    cvt_bf16<<<dim3(2048), cb, 0, stream>>>(k, S4, n4in);
    proj_gemm4<0, 0><<<gg, gb, 0, stream>>>(S4, Wkb, bk, Kh);
    cvt_bf16<<<dim3(2048), cb, 0, stream>>>(v, S4, n4in);
    proj_gemm4<1, 0><<<gg, gb, 0, stream>>>(S4, Wvb, bv, Vt);
    flash_attn5<<<dim3(LSEQ / 64, NH), gb, 0, stream>>>(Qh, Kh, Vt, S4);
    // Qh is dead now; reuse it for the bf16 copy of Wo (2 MB)
    cvt_bf16<<<dim3(1024), cb, 0, stream>>>(Wo, Qh, (1 << 18));
    proj_gemm4<2, 0><<<gg, gb, 0, stream>>>(S4, Qh, bo, (float*)d_out);
}

// Round 8
// 263.356 us; speedup vs baseline: 1.2290x; 1.1766x over previous
//
#include <hip/hip_runtime.h>
#include <hip/hip_bf16.h>
#include <math.h>

typedef unsigned short u16;
typedef unsigned int u32;
typedef u16 u16x4 __attribute__((ext_vector_type(4)));
typedef u16 u16x8 __attribute__((ext_vector_type(8)));
typedef short bf16x8 __attribute__((ext_vector_type(8)));
typedef float f32x4 __attribute__((ext_vector_type(4)));

// N=2, L=2048, E=1024, H=16, D=64
#define LSEQ 2048
#define NH   32

// Q-projection scale: 1/sqrt(64) * log2(e)  -> flash uses exp2f directly
#define QSCALE 0.18033688011112042f

__device__ __forceinline__ u16 f2bf(float f) {
    __hip_bfloat16 h = __float2bfloat16(f);
    union { __hip_bfloat16 h; u16 u; } c; c.h = h; return c.u;
}

// -----------------------------------------------------------------------
// f32 -> bf16 vectorized convert (grid-stride, float4 granularity)
// -----------------------------------------------------------------------
__global__ __launch_bounds__(256) void cvt_bf16(
    const float* __restrict__ src, u16* __restrict__ dst, int n4)
{
    int stride = gridDim.x * 256;
    for (int i = blockIdx.x * 256 + threadIdx.x; i < n4; i += stride) {
        float4 a = ((const float4*)src)[i];
        u16x4 p;
        p[0] = f2bf(a.x); p[1] = f2bf(a.y); p[2] = f2bf(a.z); p[3] = f2bf(a.w);
        ((u16x4*)dst)[i] = p;
    }
}

// three weight matrices (1M f32 each) -> contiguous bf16
__global__ __launch_bounds__(256) void cvt3_bf16(
    const float* __restrict__ s0, const float* __restrict__ s1,
    const float* __restrict__ s2, u16* __restrict__ dst)
{
    int i = blockIdx.x * 256 + threadIdx.x;      // 0 .. 3*(1<<18)-1
    const float* s = (i < (1 << 18)) ? s0 : (i < (2 << 18)) ? s1 : s2;
    int off = i & ((1 << 18) - 1);
    float4 a = ((const float4*)s)[off];
    u16x4 p;
    p[0] = f2bf(a.x); p[1] = f2bf(a.y); p[2] = f2bf(a.z); p[3] = f2bf(a.w);
    ((u16x4*)dst)[i] = p;
}

// -----------------------------------------------------------------------
// GEMM v5: C[m,n] = sum_k A[m,k]*W[n,k] + bias[n]   (A, W both bf16)
// BM=128, BN=64, BK=64; grid (16,32) = 512 blocks = 2 blocks/CU
// (launch_bounds(256,2), LDS 48KB) so a co-resident block covers each
// block's vmcnt(0)-before-barrier drain. 4 waves (2x2), wave tile 64x32:
// 16 MFMA : 12 ds_read_b128 per K-step. Linear 128B LDS rows + XOR slot
// swizzle (col16 ^= row&7), pre-swizzled SOURCE col + linear dest.
// Double-buffered, reg prologue, ONE barrier per K-step.
// MODE 0: bf16 [N,H,L,D]; MODE 1: bf16 [N,H,D,L]; MODE 2: f32 [M,E].
// QS!=0: scale output by QSCALE (Q projection).
// -----------------------------------------------------------------------
template<int MODE, int QS>
__global__ __launch_bounds__(256, 2) void proj_gemm5(
    const u16* __restrict__ A, const u16* __restrict__ W,
    const float* __restrict__ bias, void* __restrict__ Out)
{
    __shared__ u16 Al[2][128 * 64];   // 16 KB per buf
    __shared__ u16 Bl[2][64 * 64];    //  8 KB per buf

    const int tid  = threadIdx.x;
    const int lane = tid & 63;
    const int w    = tid >> 6;
    const int lr   = lane & 15, lg = lane >> 4;
    const int m0   = blockIdx.y * 128;
    const int n0   = blockIdx.x * 64;
    const int wr   = (w >> 1) * 64;
    const int wc   = (w & 1) * 32;
    const int srow = tid >> 3;                    // 0..31
    const int sc8  = tid & 7;
    const int ssw  = (sc8 ^ (srow & 7)) * 8;      // pre-swizzled source col

    f32x4 acc[4][2] = {};
    u16x8 ra[4], rb[2];

    #define LOADS(k0)                                                          \
        _Pragma("unroll")                                                      \
        for (int p_ = 0; p_ < 4; ++p_)                                         \
            ra[p_] = *(const u16x8*)(A + (size_t)(m0 + p_ * 32 + srow) * 1024  \
                                     + (k0) + ssw);                            \
        _Pragma("unroll")                                                      \
        for (int p_ = 0; p_ < 2; ++p_)                                         \
            rb[p_] = *(const u16x8*)(W + (size_t)(n0 + p_ * 32 + srow) * 1024  \
                                     + (k0) + ssw);
    #define WRITE(buf)                                                         \
        _Pragma("unroll")                                                      \
        for (int p_ = 0; p_ < 4; ++p_)                                         \
            *(u16x8*)((char*)&Al[buf][0] + (p_ * 32 + srow) * 128 + sc8 * 16)  \
                = ra[p_];                                                      \
        _Pragma("unroll")                                                      \
        for (int p_ = 0; p_ < 2; ++p_)                                         \
            *(u16x8*)((char*)&Bl[buf][0] + (p_ * 32 + srow) * 128 + sc8 * 16)  \
                = rb[p_];

    LOADS(0)
    WRITE(0)
    LOADS(64)
    __syncthreads();

    for (int t = 0; t < 16; ++t) {
        const int c = t & 1;
        if (t + 1 < 16) {
            WRITE(c ^ 1)
            if (t + 2 < 16) LOADS((t + 2) * 64)
        }
        const char* Ac = (const char*)&Al[c][0];
        const char* Bc = (const char*)&Bl[c][0];
        #pragma unroll
        for (int ks = 0; ks < 2; ++ks) {
            const int co = ((ks * 4 + lg) * 16) ^ ((lr & 7) << 4);
            bf16x8 af[4], bfr[2];
            #pragma unroll
            for (int i = 0; i < 4; ++i)
                af[i] = *(const bf16x8*)(Ac + (wr + i * 16 + lr) * 128 + co);
            #pragma unroll
            for (int j = 0; j < 2; ++j)
                bfr[j] = *(const bf16x8*)(Bc + (wc + j * 16 + lr) * 128 + co);
            #pragma unroll
            for (int i = 0; i < 4; ++i)
                #pragma unroll
                for (int j = 0; j < 2; ++j)
                    acc[i][j] = __builtin_amdgcn_mfma_f32_16x16x32_bf16(
                        af[i], bfr[j], acc[i][j], 0, 0, 0);
        }
        __syncthreads();
    }

    // epilogue
    #pragma unroll
    for (int j = 0; j < 2; ++j) {
        const int nn = n0 + wc + j * 16 + lr;
        const float bj = bias[nn];
        #pragma unroll
        for (int i = 0; i < 4; ++i) {
            #pragma unroll
            for (int r = 0; r < 4; ++r) {
                const int m = m0 + wr + i * 16 + lg * 4 + r;
                float vv = acc[i][j][r] + bj;
                if (QS) vv *= QSCALE;
                if (MODE == 0) {
                    const int n = m >> 11, l = m & 2047;
                    const int h = nn >> 6, d = nn & 63;
                    ((u16*)Out)[(((size_t)(n * 16 + h) * 2048) + l) * 64 + d] = f2bf(vv);
                } else if (MODE == 1) {
                    const int n = m >> 11, l = m & 2047;
                    const int h = nn >> 6, d = nn & 63;
                    ((u16*)Out)[(((size_t)(n * 16 + h) * 64) + d) * 2048 + l] = f2bf(vv);
                } else {
                    ((float*)Out)[(size_t)m * 1024 + nn] = vv;
                }
            }
        }
    }
    #undef LOADS
    #undef WRITE
}

// -----------------------------------------------------------------------
// Flash attention v6: block = 64 q rows; 4 waves x 16 rows; 4 blocks/CU.
// vs v5: (1) row-sum of P computed by an extra ones-B-operand MFMA into
// Oacc[4] (matrix pipe, ~free) — no shfl row-sum, no l_run chain;
// (2) wave-level defer-max: one local 15-fmax tree + 4 shfls + __all
// check vs min(m_run)+11 (log2 domain); skip all rescales on the common
// path, rare full per-row rescale otherwise. P bounded by 2^11 (safe in
// bf16/f32 accum). Everything else as v5.
// -----------------------------------------------------------------------
__global__ __launch_bounds__(256, 4) void flash_attn6(
    const u16* __restrict__ Qh, const u16* __restrict__ Kh,
    const u16* __restrict__ Vt, u16* __restrict__ Oout)
{
    const int tid  = threadIdx.x;
    const int lane = tid & 63;
    const int w    = tid >> 6;
    const int lr   = lane & 15, lg = lane >> 4;
    const int t8   = tid & 7,   td8 = tid >> 3;
    const int nh   = blockIdx.y;
    const int q0   = blockIdx.x * 64;
    const int scol = (t8 ^ (td8 & 7)) * 8;   // pre-swizzled source col (elems)

    const u16* Qb = Qh + (size_t)nh * LSEQ * 64;
    const u16* Kb = Kh + (size_t)nh * LSEQ * 64;
    const u16* Vb = Vt + (size_t)nh * 64 * LSEQ;

    __shared__ u16 Kl[2][64 * 64];   // [s][d] swizzled, 8 KB per buf
    __shared__ u16 Vl[2][64 * 64];   // [d][s] swizzled, 8 KB per buf
    __shared__ u16 Pl[4][16 * 64];   // wave-private, swizzled, 2 KB per wave

    bf16x8 aq[2];
    #pragma unroll
    for (int ks = 0; ks < 2; ++ks)
        aq[ks] = *(const bf16x8*)(Qb +
            (size_t)(q0 + w * 16 + lr) * 64 + ks * 32 + lg * 8);

    const short one_bf = (short)0x3F80;   // bf16(1.0)
    bf16x8 vones = { one_bf, one_bf, one_bf, one_bf,
                     one_bf, one_bf, one_bf, one_bf };

    float m_run[4];
    f32x4 Oacc[5] = {};   // [0..3] = P*V quadrants, [4] = P*ones (row-sum)
    #pragma unroll
    for (int r = 0; r < 4; ++r) m_run[r] = -INFINITY;

    u16x8 ldK0, ldK1, ldV0, ldV1;
    #define LOADS(s0)                                                          \
        ldK0 = *(const u16x8*)(Kb + (size_t)((s0) + td8) * 64 + scol);         \
        ldK1 = *(const u16x8*)(Kb + (size_t)((s0) + td8 + 32) * 64 + scol);    \
        ldV0 = *(const u16x8*)(Vb + (size_t)td8 * LSEQ + (s0) + scol);         \
        ldV1 = *(const u16x8*)(Vb + (size_t)(td8 + 32) * LSEQ + (s0) + scol);
    #define WRITE(buf)                                                         \
        *(u16x8*)((char*)&Kl[buf][0] + td8 * 128 + t8 * 16)        = ldK0;     \
        *(u16x8*)((char*)&Kl[buf][0] + (td8 + 32) * 128 + t8 * 16) = ldK1;     \
        *(u16x8*)((char*)&Vl[buf][0] + td8 * 128 + t8 * 16)        = ldV0;     \
        *(u16x8*)((char*)&Vl[buf][0] + (td8 + 32) * 128 + t8 * 16) = ldV1;

    LOADS(0)
    WRITE(0)
    LOADS(64)
    __syncthreads();

    for (int t = 0; t < LSEQ / 64; ++t) {
        const int c = t & 1;
        if (t + 1 < LSEQ / 64) {
            WRITE(c ^ 1)
            if (t + 2 < LSEQ / 64) LOADS((t + 2) * 64)
        }
        const char* Kc = (const char*)&Kl[c][0];
        const char* Vc = (const char*)&Vl[c][0];
        char* Pw = (char*)&Pl[w][0];

        // ---- S = Q K^T (exp2 domain) ----
        f32x4 S[4] = {};
        #pragma unroll
        for (int ks = 0; ks < 2; ++ks) {
            const int co = ((ks * 4 + lg) * 16) ^ ((lr & 7) << 4);
            #pragma unroll
            for (int ct = 0; ct < 4; ++ct) {
                bf16x8 kb = *(const bf16x8*)(Kc + (ct * 16 + lr) * 128 + co);
                S[ct] = __builtin_amdgcn_mfma_f32_16x16x32_bf16(
                    aq[ks], kb, S[ct], 0, 0, 0);
            }
        }

        // ---- defer-max online softmax ----
        {
            // local max over this lane's 16 S values
            float lm = S[0][0];
            #pragma unroll
            for (int ct = 0; ct < 4; ++ct)
                #pragma unroll
                for (int r = 0; r < 4; ++r)
                    lm = fmaxf(lm, S[ct][r]);
            // reduce over the 16 lanes of this lg group (masks 1,2,4,8):
            // = max over this group's 4 q-rows, all 64 s
            #pragma unroll
            for (int mk = 1; mk <= 8; mk <<= 1)
                lm = fmaxf(lm, __shfl_xor(lm, mk, 64));
            float mmin = fminf(fminf(m_run[0], m_run[1]),
                               fminf(m_run[2], m_run[3]));
            if (!__all((int)(lm <= mmin + 11.0f))) {
                // rare: full per-row reduce and rescale
                #pragma unroll
                for (int r = 0; r < 4; ++r) {
                    float tm = fmaxf(fmaxf(S[0][r], S[1][r]),
                                     fmaxf(S[2][r], S[3][r]));
                    #pragma unroll
                    for (int mk = 1; mk <= 8; mk <<= 1)
                        tm = fmaxf(tm, __shfl_xor(tm, mk, 64));
                    float mn = fmaxf(m_run[r], tm);
                    float sf = exp2f(m_run[r] - mn);
                    m_run[r] = mn;
                    #pragma unroll
                    for (int dt = 0; dt < 5; ++dt)
                        Oacc[dt][r] *= sf;
                }
            }
            // P = exp2(S - m) -> wave-private swizzled LDS
            #pragma unroll
            for (int ct = 0; ct < 4; ++ct)
                #pragma unroll
                for (int r = 0; r < 4; ++r) {
                    float p = exp2f(S[ct][r] - m_run[r]);
                    int pr = lg * 4 + r;
                    *(u16*)(Pw + pr * 128 +
                            (((ct * 16 + lr) * 2) ^ ((pr & 7) << 4))) = f2bf(p);
                }
        }

        // ---- O += P V  (+ row-sum via ones-MFMA) ----
        #pragma unroll
        for (int ks = 0; ks < 2; ++ks) {
            const int co = ((ks * 4 + lg) * 16) ^ ((lr & 7) << 4);
            bf16x8 pa = *(const bf16x8*)(Pw + lr * 128 + co);
            #pragma unroll
            for (int dt = 0; dt < 4; ++dt) {
                bf16x8 vb = *(const bf16x8*)(Vc + (dt * 16 + lr) * 128 + co);
                Oacc[dt] = __builtin_amdgcn_mfma_f32_16x16x32_bf16(
                    pa, vb, Oacc[dt], 0, 0, 0);
            }
            Oacc[4] = __builtin_amdgcn_mfma_f32_16x16x32_bf16(
                pa, vones, Oacc[4], 0, 0, 0);
        }
        __syncthreads();
    }
    #undef LOADS
    #undef WRITE

    // ---- epilogue: attn_out bf16 [N, L, H*D];  O / rowsum ----
    const int n = nh >> 4, h = nh & 15;
    #pragma unroll
    for (int dt = 0; dt < 4; ++dt)
        #pragma unroll
        for (int r = 0; r < 4; ++r) {
            float o = Oacc[dt][r] / Oacc[4][r];
            int qq = q0 + w * 16 + lg * 4 + r;
            Oout[((size_t)(n * LSEQ + qq)) * 1024 + h * 64 + dt * 16 + lr] = f2bf(o);
        }
}

extern "C" void kernel_launch(void* const* d_in, const int* in_sizes, int n_in,
                              void* d_out, int out_size, void* d_ws, size_t ws_size,
                              hipStream_t stream) {
    const float* q  = (const float*)d_in[0];
    const float* k  = (const float*)d_in[1];
    const float* v  = (const float*)d_in[2];
    const float* Wq = (const float*)d_in[3];
    const float* bq = (const float*)d_in[4];
    const float* Wk = (const float*)d_in[5];
    const float* bk = (const float*)d_in[6];
    const float* Wv = (const float*)d_in[7];
    const float* bv = (const float*)d_in[8];
    const float* Wo = (const float*)d_in[9];
    const float* bo = (const float*)d_in[10];

    // ws (u16 units), 32 MB: Qh | Kh | Vt | S4 (bf16 input / attn-out)
    u16* ws = (u16*)d_ws;
    u16* Qh = ws;
    u16* Kh = ws + (size_t)4 * 1024 * 1024;
    u16* Vt = ws + (size_t)8 * 1024 * 1024;
    u16* S4 = ws + (size_t)12 * 1024 * 1024;

    // d_out (16 MB f32) doubles as scratch until the final GEMM fully
    // overwrites it: Wq/Wk/Wv bf16 copies live in its first 6 MB.
    u16* Wb  = (u16*)d_out;
    u16* Wqb = Wb;
    u16* Wkb = Wb + (size_t)1 * 1024 * 1024;
    u16* Wvb = Wb + (size_t)2 * 1024 * 1024;

    const int n4in = (2 * LSEQ * 1024) / 4;  // q/k/v: 2M float4
    dim3 cb(256);
    dim3 gg(16, 32), gb(256);                // GEMM: x = N/64, y = M/128

    cvt3_bf16<<<dim3(3 * 1024), cb, 0, stream>>>(Wq, Wk, Wv, Wb);
    cvt_bf16<<<dim3(2048), cb, 0, stream>>>(q, S4, n4in);
    proj_gemm5<0, 1><<<gg, gb, 0, stream>>>(S4, Wqb, bq, Qh);
    cvt_bf16<<<dim3(2048), cb, 0, stream>>>(k, S4, n4in);
    proj_gemm5<0, 0><<<gg, gb, 0, stream>>>(S4, Wkb, bk, Kh);
    cvt_bf16<<<dim3(2048), cb, 0, stream>>>(v, S4, n4in);
    proj_gemm5<1, 0><<<gg, gb, 0, stream>>>(S4, Wvb, bv, Vt);
    flash_attn6<<<dim3(LSEQ / 64, NH), gb, 0, stream>>>(Qh, Kh, Vt, S4);
    // Qh is dead now; reuse it for the bf16 copy of Wo (2 MB)
    cvt_bf16<<<dim3(1024), cb, 0, stream>>>(Wo, Qh, (1 << 18));
    proj_gemm5<2, 0><<<gg, gb, 0, stream>>>(S4, Qh, bo, (float*)d_out);
}

// Round 9
// 254.244 us; speedup vs baseline: 1.2731x; 1.0358x over previous
//
#include <hip/hip_runtime.h>
#include <hip/hip_bf16.h>
#include <math.h>

typedef unsigned short u16;
typedef unsigned int u32;
typedef u16 u16x4 __attribute__((ext_vector_type(4)));
typedef u16 u16x8 __attribute__((ext_vector_type(8)));
typedef short bf16x8 __attribute__((ext_vector_type(8)));
typedef float f32x4 __attribute__((ext_vector_type(4)));

// N=2, L=2048, E=1024, H=16, D=64
#define LSEQ 2048
#define NH   32

// Q-projection scale: 1/sqrt(64) * log2(e)  -> flash uses exp2f directly
#define QSCALE 0.18033688011112042f

__device__ __forceinline__ u16 f2bf(float f) {
    __hip_bfloat16 h = __float2bfloat16(f);
    union { __hip_bfloat16 h; u16 u; } c; c.h = h; return c.u;
}

// -----------------------------------------------------------------------
// f32 -> bf16 vectorized convert (grid-stride, float4 granularity)
// -----------------------------------------------------------------------
__global__ __launch_bounds__(256) void cvt_bf16(
    const float* __restrict__ src, u16* __restrict__ dst, int n4)
{
    int stride = gridDim.x * 256;
    for (int i = blockIdx.x * 256 + threadIdx.x; i < n4; i += stride) {
        float4 a = ((const float4*)src)[i];
        u16x4 p;
        p[0] = f2bf(a.x); p[1] = f2bf(a.y); p[2] = f2bf(a.z); p[3] = f2bf(a.w);
        ((u16x4*)dst)[i] = p;
    }
}

// three weight matrices (1M f32 each) -> contiguous bf16
__global__ __launch_bounds__(256) void cvt3_bf16(
    const float* __restrict__ s0, const float* __restrict__ s1,
    const float* __restrict__ s2, u16* __restrict__ dst)
{
    int i = blockIdx.x * 256 + threadIdx.x;      // 0 .. 3*(1<<18)-1
    const float* s = (i < (1 << 18)) ? s0 : (i < (2 << 18)) ? s1 : s2;
    int off = i & ((1 << 18) - 1);
    float4 a = ((const float4*)s)[off];
    u16x4 p;
    p[0] = f2bf(a.x); p[1] = f2bf(a.y); p[2] = f2bf(a.z); p[3] = f2bf(a.w);
    ((u16x4*)dst)[i] = p;
}

// -----------------------------------------------------------------------
// GEMM v5 + XCD swizzle: C[m,n] = sum_k A[m,k]*W[n,k] + bias[n] (bf16 in)
// BM=128, BN=64, BK=64; grid 512 = 2 blocks/CU. XCD-grouped block swizzle:
// flat=(by*16+bx); swz=(flat&7)*64+(flat>>3) -> XCD c owns 4 contiguous
// m-panels x all n-tiles, so its working set (4 A-panels 1MB + W 2MB)
// stays L2-resident instead of re-fetching ~190MB from L3/HBM.
// 4 waves (2x2), wave tile 64x32. Linear 128B LDS rows + XOR slot swizzle
// (col16 ^= row&7), pre-swizzled SOURCE col + linear dest. Double-
// buffered, reg prologue, ONE barrier per K-step.
// MODE 0: bf16 [N,H,L,D]; MODE 1: bf16 [N,H,D,L]; MODE 2: f32 [M,E].
// QS!=0: scale output by QSCALE (Q projection).
// -----------------------------------------------------------------------
template<int MODE, int QS>
__global__ __launch_bounds__(256, 2) void proj_gemm5(
    const u16* __restrict__ A, const u16* __restrict__ W,
    const float* __restrict__ bias, void* __restrict__ Out)
{
    __shared__ u16 Al[2][128 * 64];   // 16 KB per buf
    __shared__ u16 Bl[2][64 * 64];    //  8 KB per buf

    const int tid  = threadIdx.x;
    const int lane = tid & 63;
    const int w    = tid >> 6;
    const int lr   = lane & 15, lg = lane >> 4;
    // XCD-grouped bijective swizzle (512 = 8 x 64 exact)
    const int flat = blockIdx.y * 16 + blockIdx.x;
    const int swz  = (flat & 7) * 64 + (flat >> 3);
    const int m0   = (swz >> 4) * 128;
    const int n0   = (swz & 15) * 64;
    const int wr   = (w >> 1) * 64;
    const int wc   = (w & 1) * 32;
    const int srow = tid >> 3;                    // 0..31
    const int sc8  = tid & 7;
    const int ssw  = (sc8 ^ (srow & 7)) * 8;      // pre-swizzled source col

    f32x4 acc[4][2] = {};
    u16x8 ra[4], rb[2];

    #define LOADS(k0)                                                          \
        _Pragma("unroll")                                                      \
        for (int p_ = 0; p_ < 4; ++p_)                                         \
            ra[p_] = *(const u16x8*)(A + (size_t)(m0 + p_ * 32 + srow) * 1024  \
                                     + (k0) + ssw);                            \
        _Pragma("unroll")                                                      \
        for (int p_ = 0; p_ < 2; ++p_)                                         \
            rb[p_] = *(const u16x8*)(W + (size_t)(n0 + p_ * 32 + srow) * 1024  \
                                     + (k0) + ssw);
    #define WRITE(buf)                                                         \
        _Pragma("unroll")                                                      \
        for (int p_ = 0; p_ < 4; ++p_)                                         \
            *(u16x8*)((char*)&Al[buf][0] + (p_ * 32 + srow) * 128 + sc8 * 16)  \
                = ra[p_];                                                      \
        _Pragma("unroll")                                                      \
        for (int p_ = 0; p_ < 2; ++p_)                                         \
            *(u16x8*)((char*)&Bl[buf][0] + (p_ * 32 + srow) * 128 + sc8 * 16)  \
                = rb[p_];

    LOADS(0)
    WRITE(0)
    LOADS(64)
    __syncthreads();

    for (int t = 0; t < 16; ++t) {
        const int c = t & 1;
        if (t + 1 < 16) {
            WRITE(c ^ 1)
            if (t + 2 < 16) LOADS((t + 2) * 64)
        }
        const char* Ac = (const char*)&Al[c][0];
        const char* Bc = (const char*)&Bl[c][0];
        #pragma unroll
        for (int ks = 0; ks < 2; ++ks) {
            const int co = ((ks * 4 + lg) * 16) ^ ((lr & 7) << 4);
            bf16x8 af[4], bfr[2];
            #pragma unroll
            for (int i = 0; i < 4; ++i)
                af[i] = *(const bf16x8*)(Ac + (wr + i * 16 + lr) * 128 + co);
            #pragma unroll
            for (int j = 0; j < 2; ++j)
                bfr[j] = *(const bf16x8*)(Bc + (wc + j * 16 + lr) * 128 + co);
            #pragma unroll
            for (int i = 0; i < 4; ++i)
                #pragma unroll
                for (int j = 0; j < 2; ++j)
                    acc[i][j] = __builtin_amdgcn_mfma_f32_16x16x32_bf16(
                        af[i], bfr[j], acc[i][j], 0, 0, 0);
        }
        __syncthreads();
    }

    // epilogue
    #pragma unroll
    for (int j = 0; j < 2; ++j) {
        const int nn = n0 + wc + j * 16 + lr;
        const float bj = bias[nn];
        #pragma unroll
        for (int i = 0; i < 4; ++i) {
            #pragma unroll
            for (int r = 0; r < 4; ++r) {
                const int m = m0 + wr + i * 16 + lg * 4 + r;
                float vv = acc[i][j][r] + bj;
                if (QS) vv *= QSCALE;
                if (MODE == 0) {
                    const int n = m >> 11, l = m & 2047;
                    const int h = nn >> 6, d = nn & 63;
                    ((u16*)Out)[(((size_t)(n * 16 + h) * 2048) + l) * 64 + d] = f2bf(vv);
                } else if (MODE == 1) {
                    const int n = m >> 11, l = m & 2047;
                    const int h = nn >> 6, d = nn & 63;
                    ((u16*)Out)[(((size_t)(n * 16 + h) * 64) + d) * 2048 + l] = f2bf(vv);
                } else {
                    ((float*)Out)[(size_t)m * 1024 + nn] = vv;
                }
            }
        }
    }
    #undef LOADS
    #undef WRITE
}

// -----------------------------------------------------------------------
// Flash attention v6 + XCD swizzle: block = 64 q rows; 4 waves x 16 rows.
// XCD-grouped swizzle: flat=(by*32+bx); swz=(flat&7)*128+(flat>>3) ->
// XCD c owns 4 heads x all q-tiles, so K/V (4 x 512KB = 2MB) stays
// L2-resident. Row-sum via ones-MFMA; wave-level defer-max. As R8.
// -----------------------------------------------------------------------
__global__ __launch_bounds__(256, 4) void flash_attn6(
    const u16* __restrict__ Qh, const u16* __restrict__ Kh,
    const u16* __restrict__ Vt, u16* __restrict__ Oout)
{
    const int tid  = threadIdx.x;
    const int lane = tid & 63;
    const int w    = tid >> 6;
    const int lr   = lane & 15, lg = lane >> 4;
    const int t8   = tid & 7,   td8 = tid >> 3;
    // XCD-grouped bijective swizzle (1024 = 8 x 128 exact)
    const int flat = blockIdx.y * 32 + blockIdx.x;
    const int swz  = (flat & 7) * 128 + (flat >> 3);
    const int nh   = swz >> 5;
    const int q0   = (swz & 31) * 64;
    const int scol = (t8 ^ (td8 & 7)) * 8;   // pre-swizzled source col (elems)

    const u16* Qb = Qh + (size_t)nh * LSEQ * 64;
    const u16* Kb = Kh + (size_t)nh * LSEQ * 64;
    const u16* Vb = Vt + (size_t)nh * 64 * LSEQ;

    __shared__ u16 Kl[2][64 * 64];   // [s][d] swizzled, 8 KB per buf
    __shared__ u16 Vl[2][64 * 64];   // [d][s] swizzled, 8 KB per buf
    __shared__ u16 Pl[4][16 * 64];   // wave-private, swizzled, 2 KB per wave

    bf16x8 aq[2];
    #pragma unroll
    for (int ks = 0; ks < 2; ++ks)
        aq[ks] = *(const bf16x8*)(Qb +
            (size_t)(q0 + w * 16 + lr) * 64 + ks * 32 + lg * 8);

    const short one_bf = (short)0x3F80;   // bf16(1.0)
    bf16x8 vones = { one_bf, one_bf, one_bf, one_bf,
                     one_bf, one_bf, one_bf, one_bf };

    float m_run[4];
    f32x4 Oacc[5] = {};   // [0..3] = P*V quadrants, [4] = P*ones (row-sum)
    #pragma unroll
    for (int r = 0; r < 4; ++r) m_run[r] = -INFINITY;

    u16x8 ldK0, ldK1, ldV0, ldV1;
    #define LOADS(s0)                                                          \
        ldK0 = *(const u16x8*)(Kb + (size_t)((s0) + td8) * 64 + scol);         \
        ldK1 = *(const u16x8*)(Kb + (size_t)((s0) + td8 + 32) * 64 + scol);    \
        ldV0 = *(const u16x8*)(Vb + (size_t)td8 * LSEQ + (s0) + scol);         \
        ldV1 = *(const u16x8*)(Vb + (size_t)(td8 + 32) * LSEQ + (s0) + scol);
    #define WRITE(buf)                                                         \
        *(u16x8*)((char*)&Kl[buf][0] + td8 * 128 + t8 * 16)        = ldK0;     \
        *(u16x8*)((char*)&Kl[buf][0] + (td8 + 32) * 128 + t8 * 16) = ldK1;     \
        *(u16x8*)((char*)&Vl[buf][0] + td8 * 128 + t8 * 16)        = ldV0;     \
        *(u16x8*)((char*)&Vl[buf][0] + (td8 + 32) * 128 + t8 * 16) = ldV1;

    LOADS(0)
    WRITE(0)
    LOADS(64)
    __syncthreads();

    for (int t = 0; t < LSEQ / 64; ++t) {
        const int c = t & 1;
        if (t + 1 < LSEQ / 64) {
            WRITE(c ^ 1)
            if (t + 2 < LSEQ / 64) LOADS((t + 2) * 64)
        }
        const char* Kc = (const char*)&Kl[c][0];
        const char* Vc = (const char*)&Vl[c][0];
        char* Pw = (char*)&Pl[w][0];

        // ---- S = Q K^T (exp2 domain) ----
        f32x4 S[4] = {};
        #pragma unroll
        for (int ks = 0; ks < 2; ++ks) {
            const int co = ((ks * 4 + lg) * 16) ^ ((lr & 7) << 4);
            #pragma unroll
            for (int ct = 0; ct < 4; ++ct) {
                bf16x8 kb = *(const bf16x8*)(Kc + (ct * 16 + lr) * 128 + co);
                S[ct] = __builtin_amdgcn_mfma_f32_16x16x32_bf16(
                    aq[ks], kb, S[ct], 0, 0, 0);
            }
        }

        // ---- defer-max online softmax ----
        {
            float lm = S[0][0];
            #pragma unroll
            for (int ct = 0; ct < 4; ++ct)
                #pragma unroll
                for (int r = 0; r < 4; ++r)
                    lm = fmaxf(lm, S[ct][r]);
            #pragma unroll
            for (int mk = 1; mk <= 8; mk <<= 1)
                lm = fmaxf(lm, __shfl_xor(lm, mk, 64));
            float mmin = fminf(fminf(m_run[0], m_run[1]),
                               fminf(m_run[2], m_run[3]));
            if (!__all((int)(lm <= mmin + 11.0f))) {
                #pragma unroll
                for (int r = 0; r < 4; ++r) {
                    float tm = fmaxf(fmaxf(S[0][r], S[1][r]),
                                     fmaxf(S[2][r], S[3][r]));
                    #pragma unroll
                    for (int mk = 1; mk <= 8; mk <<= 1)
                        tm = fmaxf(tm, __shfl_xor(tm, mk, 64));
                    float mn = fmaxf(m_run[r], tm);
                    float sf = exp2f(m_run[r] - mn);
                    m_run[r] = mn;
                    #pragma unroll
                    for (int dt = 0; dt < 5; ++dt)
                        Oacc[dt][r] *= sf;
                }
            }
            #pragma unroll
            for (int ct = 0; ct < 4; ++ct)
                #pragma unroll
                for (int r = 0; r < 4; ++r) {
                    float p = exp2f(S[ct][r] - m_run[r]);
                    int pr = lg * 4 + r;
                    *(u16*)(Pw + pr * 128 +
                            (((ct * 16 + lr) * 2) ^ ((pr & 7) << 4))) = f2bf(p);
                }
        }

        // ---- O += P V  (+ row-sum via ones-MFMA) ----
        #pragma unroll
        for (int ks = 0; ks < 2; ++ks) {
            const int co = ((ks * 4 + lg) * 16) ^ ((lr & 7) << 4);
            bf16x8 pa = *(const bf16x8*)(Pw + lr * 128 + co);
            #pragma unroll
            for (int dt = 0; dt < 4; ++dt) {
                bf16x8 vb = *(const bf16x8*)(Vc + (dt * 16 + lr) * 128 + co);
                Oacc[dt] = __builtin_amdgcn_mfma_f32_16x16x32_bf16(
                    pa, vb, Oacc[dt], 0, 0, 0);
            }
            Oacc[4] = __builtin_amdgcn_mfma_f32_16x16x32_bf16(
                pa, vones, Oacc[4], 0, 0, 0);
        }
        __syncthreads();
    }
    #undef LOADS
    #undef WRITE

    // ---- epilogue: attn_out bf16 [N, L, H*D];  O / rowsum ----
    const int n = nh >> 4, h = nh & 15;
    #pragma unroll
    for (int dt = 0; dt < 4; ++dt)
        #pragma unroll
        for (int r = 0; r < 4; ++r) {
            float o = Oacc[dt][r] / Oacc[4][r];
            int qq = q0 + w * 16 + lg * 4 + r;
            Oout[((size_t)(n * LSEQ + qq)) * 1024 + h * 64 + dt * 16 + lr] = f2bf(o);
        }
}

extern "C" void kernel_launch(void* const* d_in, const int* in_sizes, int n_in,
                              void* d_out, int out_size, void* d_ws, size_t ws_size,
                              hipStream_t stream) {
    const float* q  = (const float*)d_in[0];
    const float* k  = (const float*)d_in[1];
    const float* v  = (const float*)d_in[2];
    const float* Wq = (const float*)d_in[3];
    const float* bq = (const float*)d_in[4];
    const float* Wk = (const float*)d_in[5];
    const float* bk = (const float*)d_in[6];
    const float* Wv = (const float*)d_in[7];
    const float* bv = (const float*)d_in[8];
    const float* Wo = (const float*)d_in[9];
    const float* bo = (const float*)d_in[10];

    // ws (u16 units), 32 MB: Qh | Kh | Vt | S4 (bf16 input / attn-out)
    u16* ws = (u16*)d_ws;
    u16* Qh = ws;
    u16* Kh = ws + (size_t)4 * 1024 * 1024;
    u16* Vt = ws + (size_t)8 * 1024 * 1024;
    u16* S4 = ws + (size_t)12 * 1024 * 1024;

    // d_out (16 MB f32) doubles as scratch until the final GEMM fully
    // overwrites it: Wq/Wk/Wv bf16 copies live in its first 6 MB.
    u16* Wb  = (u16*)d_out;
    u16* Wqb = Wb;
    u16* Wkb = Wb + (size_t)1 * 1024 * 1024;
    u16* Wvb = Wb + (size_t)2 * 1024 * 1024;

    const int n4in = (2 * LSEQ * 1024) / 4;  // q/k/v: 2M float4
    dim3 cb(256);
    dim3 gg(16, 32), gb(256);                // GEMM: x = N/64, y = M/128

    cvt3_bf16<<<dim3(3 * 1024), cb, 0, stream>>>(Wq, Wk, Wv, Wb);
    cvt_bf16<<<dim3(2048), cb, 0, stream>>>(q, S4, n4in);
    proj_gemm5<0, 1><<<gg, gb, 0, stream>>>(S4, Wqb, bq, Qh);
    cvt_bf16<<<dim3(2048), cb, 0, stream>>>(k, S4, n4in);
    proj_gemm5<0, 0><<<gg, gb, 0, stream>>>(S4, Wkb, bk, Kh);
    cvt_bf16<<<dim3(2048), cb, 0, stream>>>(v, S4, n4in);
    proj_gemm5<1, 0><<<gg, gb, 0, stream>>>(S4, Wvb, bv, Vt);
    flash_attn6<<<dim3(LSEQ / 64, NH), gb, 0, stream>>>(Qh, Kh, Vt, S4);
    // Qh is dead now; reuse it for the bf16 copy of Wo (2 MB)
    cvt_bf16<<<dim3(1024), cb, 0, stream>>>(Wo, Qh, (1 << 18));
    proj_gemm5<2, 0><<<gg, gb, 0, stream>>>(S4, Qh, bo, (float*)d_out);
}